// Round 7
// baseline (112.834 us; speedup 1.0000x reference)
//
#include <hip/hip_runtime.h>

#define HID 20

typedef _Float16 half8  __attribute__((ext_vector_type(8)));
typedef _Float16 half2t __attribute__((ext_vector_type(2)));
typedef float    f32x16 __attribute__((ext_vector_type(16)));

union H8 { half8 v8; half2t d[4]; };   // build fp16 fragment dword-by-dword

// tanh via exp2 + rcp: tanh(v) = 1 - 2/(exp2(v*2*log2e)+1). Saturates at +-inf.
static __device__ __forceinline__ float tanh_fast(float v) {
    const float e = __builtin_amdgcn_exp2f(v * 2.8853900817779268f);
    const float r = __builtin_amdgcn_rcpf(e + 1.0f);
    return fmaf(-2.0f, r, 1.0f);
}

// v_cvt_pkrtz_f16_f32: pack two f32 into one dword of two fp16 (RTZ).
static __device__ __forceinline__ half2t pk(float a, float b) {
    auto r = __builtin_amdgcn_cvt_pkrtz(a, b);
    half2t out;
    __builtin_memcpy(&out, &r, sizeof(out));
    return out;
}

// v_permlane32_swap_b32: new_x[l>=32] = old_y[l-32]; new_y[l<32] = old_x[l+32].
static __device__ __forceinline__ void swap_halves(float& x, float& y) {
    asm("v_permlane32_swap_b32 %0, %1" : "+v"(x), "+v"(y));
}

// sum with lane^32 partner on every lane: permlane-based, no LDS wait.
static __device__ __forceinline__ float xor32_sum(float u) {
    float t = u;
    swap_halves(u, t);     // u[l] = old_u[l&31]; t[l] = old_u[32|(l&31)]
    return u + t;
}

// 64-lane shuffle reduce -> cross-wave LDS -> one f64 atomic per block.
__device__ __forceinline__ void block_reduce_atomic(float local, double* dst) {
    #pragma unroll
    for (int off = 32; off > 0; off >>= 1) local += __shfl_down(local, off);
    __shared__ float parts[4];
    __syncthreads();
    const int lane = threadIdx.x & 63, wid = threadIdx.x >> 6;
    if (lane == 0) parts[wid] = local;
    __syncthreads();
    if (threadIdx.x == 0)
        atomicAdd(dst, (double)(parts[0] + parts[1] + parts[2] + parts[3]));
}

// ---------------------------------------------------------------------------
// Fused persistent kernel, grid = CBLK+DBLK = 1024 = 4 blocks/CU x 256 CUs.
// Blocks [0, CBLK): collocation (4 dual channels).
// Blocks [CBLK, CBLK+DBLK): initial+boundary (value only).
// Swapped MFMA orientation: D = Wt * Ht, point = column = lane&31 for B and D.
//   A (Wt): M-row = lane&31 (out neuron), k = 16c + 8h + e (in neuron);
//           k==20 carries the bias; rows/cols >= 20 are zero.
//   D:      col = lane&31 (point), row = (r&3) + 8(r>>2) + 4h.
// Rows >= 20 of D are exactly 0 => epilogue only r<12; pack c=1 needs no swap.
// __launch_bounds__(256,4): force <=128 arch+acc regs -> 4 waves/SIMD.
// ---------------------------------------------------------------------------
__global__ __launch_bounds__(256, 4) void k_fused(
    const float* __restrict__ t_c, const float* __restrict__ x_c,
    const float* __restrict__ t_i, const float* __restrict__ x_i, const float* __restrict__ u_i,
    const float* __restrict__ t_b, const float* __restrict__ x_b, const float* __restrict__ u_b,
    const float* __restrict__ W1, const float* __restrict__ b1,
    const float* __restrict__ W2, const float* __restrict__ b2,
    const float* __restrict__ W3, const float* __restrict__ b3,
    const float* __restrict__ W4, const float* __restrict__ b4,
    double* __restrict__ sums,
    int N, int NI, int NB, int CBLK, int DBLK, float nu)
{
    __shared__ float4 sL[32];          // {W1_t, W1_x, b1, 0} per layer-1 slot
    const int tid = threadIdx.x;
    if (tid < 32) {
        const bool r = tid < HID;
        sL[tid] = make_float4(r ? W1[tid] : 0.f, r ? W1[HID + tid] : 0.f,
                              r ? b1[tid] : 0.f, 0.f);
    }
    __syncthreads();

    const int lane = tid & 63;
    const int h    = lane >> 5;
    const int colp = lane & 31;

    // A fragments for W2,W3 (+bias row k=20); W4 packed fp16 (6 regs)
    half8 A2[2], A3[2];
    #pragma unroll
    for (int c = 0; c < 2; ++c) {
        #pragma unroll
        for (int e = 0; e < 8; ++e) {
            const int i = 16 * c + 8 * h + e;
            float v2 = 0.f, v3 = 0.f;
            if (colp < HID) {
                if (i < HID)       { v2 = W2[i * HID + colp]; v3 = W3[i * HID + colp]; }
                else if (i == HID) { v2 = b2[colp];           v3 = b3[colp]; }
            }
            A2[c][e] = (_Float16)v2;
            A3[c][e] = (_Float16)v3;
        }
    }
    half2t w4h[6];
    #pragma unroll
    for (int j = 0; j < 6; ++j) {
        const int r0 = 2 * j, r1 = 2 * j + 1;
        const int row0 = (r0 & 3) + 8 * (r0 >> 2) + 4 * h;
        const int row1 = (r1 & 3) + 8 * (r1 >> 2) + 4 * h;
        w4h[j] = pk((row0 < HID) ? W4[row0] : 0.f, (row1 < HID) ? W4[row1] : 0.f);
    }
    const float b4v = b4[0];
    const half2t Z2   = {(_Float16)0.0f, (_Float16)0.0f};
    const half2t ONE0 = {(_Float16)1.0f, (_Float16)0.0f};
    // persistent zero accumulator: C operand of each channel's first MFMA chunk
    f32x16 FZ;
    #pragma unroll
    for (int r = 0; r < 16; ++r) FZ[r] = 0.0f;

    if ((int)blockIdx.x < CBLK) {
        // ================= collocation: 4 dual channels =================
        const int wave  = (int)blockIdx.x * 4 + (tid >> 6);
        const int nwave = CBLK * 4;
        const int ntile = (N + 31) >> 5;

        float local = 0.0f;
        for (int tile = wave; tile < ntile; tile += nwave) {
            const int  idx   = (tile << 5) + colp;
            const bool valid = idx < N;
            const int  ia    = valid ? idx : 0;
            const float tv = t_c[ia], xv = x_c[ia];

            // layer-1 slot: p = t*w.x + x*w.y + w.z ; duals from (w.x, w.y)
            auto l1 = [&](int e, int c, float& vv, float& va, float& vc, float& ve) {
                const int n = 16 * c + 8 * h + e;
                const float4 w = sL[n];
                const float p  = fmaf(tv, w.x, fmaf(xv, w.y, w.z));
                const float th = tanh_fast(p);
                const float s  = fmaf(-th, th, 1.0f);
                const float q  = s * w.y;
                vv = th; va = s * w.x; vc = q; ve = -((th + th) * q) * w.y;
            };

            H8 Bv[2], Ba[2], Bc[2], Be[2];
            #pragma unroll
            for (int d2 = 0; d2 < 4; ++d2) {       // c=0, slot pairs
                float v0,a0,c0,e0, v1,a1,c1,e1;
                l1(2*d2,     0, v0,a0,c0,e0);
                l1(2*d2 + 1, 0, v1,a1,c1,e1);
                Bv[0].d[d2] = pk(v0,v1); Ba[0].d[d2] = pk(a0,a1);
                Bc[0].d[d2] = pk(c0,c1); Be[0].d[d2] = pk(e0,e1);
            }
            #pragma unroll
            for (int d2 = 0; d2 < 2; ++d2) {       // c=1, slots 16..19
                float v0,a0,c0,e0, v1,a1,c1,e1;
                l1(2*d2,     1, v0,a0,c0,e0);
                l1(2*d2 + 1, 1, v1,a1,c1,e1);
                Bv[1].d[d2] = pk(v0,v1); Ba[1].d[d2] = pk(a0,a1);
                Bc[1].d[d2] = pk(c0,c1); Be[1].d[d2] = pk(e0,e1);
            }
            Bv[1].d[2] = ONE0; Ba[1].d[2] = Z2; Bc[1].d[2] = Z2; Be[1].d[2] = Z2; // bias k=20
            Bv[1].d[3] = Z2;   Ba[1].d[3] = Z2; Bc[1].d[3] = Z2; Be[1].d[3] = Z2;

            // ---- layer 2: first chunk takes FZ as C (no per-tile zeroing) ----
            f32x16 Dv, Da, Dc, De;
            __builtin_amdgcn_s_setprio(1);
            Dv = __builtin_amdgcn_mfma_f32_32x32x16_f16(A2[0], Bv[0].v8, FZ, 0,0,0);
            Da = __builtin_amdgcn_mfma_f32_32x32x16_f16(A2[0], Ba[0].v8, FZ, 0,0,0);
            Dc = __builtin_amdgcn_mfma_f32_32x32x16_f16(A2[0], Bc[0].v8, FZ, 0,0,0);
            De = __builtin_amdgcn_mfma_f32_32x32x16_f16(A2[0], Be[0].v8, FZ, 0,0,0);
            Dv = __builtin_amdgcn_mfma_f32_32x32x16_f16(A2[1], Bv[1].v8, Dv, 0,0,0);
            Da = __builtin_amdgcn_mfma_f32_32x32x16_f16(A2[1], Ba[1].v8, Da, 0,0,0);
            Dc = __builtin_amdgcn_mfma_f32_32x32x16_f16(A2[1], Bc[1].v8, Dc, 0,0,0);
            De = __builtin_amdgcn_mfma_f32_32x32x16_f16(A2[1], Be[1].v8, De, 0,0,0);
            __builtin_amdgcn_s_setprio(0);

            #pragma unroll
            for (int r = 0; r < 12; ++r) {          // rows >=24 are dead
                const float zv = Dv[r], za = Da[r], zc = Dc[r], ze = De[r];
                const float th = tanh_fast(zv);
                const float s  = fmaf(-th, th, 1.0f);
                const float q  = s * zc;
                Dv[r] = th; Da[r] = s * za; Dc[r] = q;
                De[r] = fmaf(s, ze, -((th + th) * q) * zc);
            }
            // pack D -> B: c=0 via swaps; c=1 straight (h=1 side is natural 0)
            #pragma unroll
            for (int d2 = 0; d2 < 2; ++d2) {
                float x0,y0,x1,y1;
                x0=Dv[2*d2]; y0=Dv[4+2*d2]; swap_halves(x0,y0);
                x1=Dv[2*d2+1]; y1=Dv[5+2*d2]; swap_halves(x1,y1);
                Bv[0].d[d2] = pk(x0,x1); Bv[0].d[2+d2] = pk(y0,y1);
                x0=Da[2*d2]; y0=Da[4+2*d2]; swap_halves(x0,y0);
                x1=Da[2*d2+1]; y1=Da[5+2*d2]; swap_halves(x1,y1);
                Ba[0].d[d2] = pk(x0,x1); Ba[0].d[2+d2] = pk(y0,y1);
                x0=Dc[2*d2]; y0=Dc[4+2*d2]; swap_halves(x0,y0);
                x1=Dc[2*d2+1]; y1=Dc[5+2*d2]; swap_halves(x1,y1);
                Bc[0].d[d2] = pk(x0,x1); Bc[0].d[2+d2] = pk(y0,y1);
                x0=De[2*d2]; y0=De[4+2*d2]; swap_halves(x0,y0);
                x1=De[2*d2+1]; y1=De[5+2*d2]; swap_halves(x1,y1);
                Be[0].d[d2] = pk(x0,x1); Be[0].d[2+d2] = pk(y0,y1);
            }
            Bv[1].d[0] = pk(Dv[8],Dv[9]); Bv[1].d[1] = pk(Dv[10],Dv[11]);
            Ba[1].d[0] = pk(Da[8],Da[9]); Ba[1].d[1] = pk(Da[10],Da[11]);
            Bc[1].d[0] = pk(Dc[8],Dc[9]); Bc[1].d[1] = pk(Dc[10],Dc[11]);
            Be[1].d[0] = pk(De[8],De[9]); Be[1].d[1] = pk(De[10],De[11]);
            Bv[1].d[2] = ONE0; Ba[1].d[2] = Z2; Bc[1].d[2] = Z2; Be[1].d[2] = Z2;
            Bv[1].d[3] = Z2;   Ba[1].d[3] = Z2; Bc[1].d[3] = Z2; Be[1].d[3] = Z2;

            // ---- layer 3 ----
            __builtin_amdgcn_s_setprio(1);
            Dv = __builtin_amdgcn_mfma_f32_32x32x16_f16(A3[0], Bv[0].v8, FZ, 0,0,0);
            Da = __builtin_amdgcn_mfma_f32_32x32x16_f16(A3[0], Ba[0].v8, FZ, 0,0,0);
            Dc = __builtin_amdgcn_mfma_f32_32x32x16_f16(A3[0], Bc[0].v8, FZ, 0,0,0);
            De = __builtin_amdgcn_mfma_f32_32x32x16_f16(A3[0], Be[0].v8, FZ, 0,0,0);
            Dv = __builtin_amdgcn_mfma_f32_32x32x16_f16(A3[1], Bv[1].v8, Dv, 0,0,0);
            Da = __builtin_amdgcn_mfma_f32_32x32x16_f16(A3[1], Ba[1].v8, Da, 0,0,0);
            Dc = __builtin_amdgcn_mfma_f32_32x32x16_f16(A3[1], Bc[1].v8, Dc, 0,0,0);
            De = __builtin_amdgcn_mfma_f32_32x32x16_f16(A3[1], Be[1].v8, De, 0,0,0);
            __builtin_amdgcn_s_setprio(0);

            #pragma unroll
            for (int r = 0; r < 12; ++r) {
                const float zv = Dv[r], za = Da[r], zc = Dc[r], ze = De[r];
                const float th = tanh_fast(zv);
                const float s  = fmaf(-th, th, 1.0f);
                const float q  = s * zc;
                Dv[r] = th; Da[r] = s * za; Dc[r] = q;
                De[r] = fmaf(s, ze, -((th + th) * q) * zc);
            }

            float u = 0.f, ut = 0.f, ux = 0.f, uxx = 0.f;
            #pragma unroll
            for (int j = 0; j < 6; ++j) {
                const float wa = (float)w4h[j][0], wb = (float)w4h[j][1];
                u   = fmaf(wa, Dv[2*j], fmaf(wb, Dv[2*j+1], u));
                ut  = fmaf(wa, Da[2*j], fmaf(wb, Da[2*j+1], ut));
                ux  = fmaf(wa, Dc[2*j], fmaf(wb, Dc[2*j+1], ux));
                uxx = fmaf(wa, De[2*j], fmaf(wb, De[2*j+1], uxx));
            }
            u   = xor32_sum(u) + b4v;
            ut  = xor32_sum(ut);
            ux  = xor32_sum(ux);
            uxx = xor32_sum(uxx);

            float f = fmaf(u, ux, ut);
            f = fmaf(-nu, uxx, f);
            if (h == 0 && valid) local += f * f;
        }
        block_reduce_atomic(local, sums + 0);
    } else {
        // ============== initial + boundary: value channel only ==============
        const int dwave = ((int)blockIdx.x - CBLK) * 4 + (tid >> 6);
        const int dnw   = DBLK * 4;
        const int nti   = (NI + 31) >> 5;
        const int ntb   = (NB + 31) >> 5;

        float li = 0.0f, lbd = 0.0f;
        for (int t2 = dwave; t2 < nti + ntb; t2 += dnw) {
            const bool isB = t2 >= nti;               // wave-uniform
            const float* tp = isB ? t_b : t_i;
            const float* xp = isB ? x_b : x_i;
            const float* up = isB ? u_b : u_i;
            const int    n_ = isB ? NB  : NI;
            const int  idx  = (((isB ? t2 - nti : t2) << 5)) + colp;
            const bool valid = idx < n_;
            const int  ia    = valid ? idx : 0;
            const float tv = tp[ia], xv = xp[ia], uT = up[ia];

            auto l1v = [&](int e, int c) -> float {
                const int n = 16 * c + 8 * h + e;
                const float4 w = sL[n];
                return tanh_fast(fmaf(tv, w.x, fmaf(xv, w.y, w.z)));
            };

            H8 Bv[2];
            #pragma unroll
            for (int d2 = 0; d2 < 4; ++d2)
                Bv[0].d[d2] = pk(l1v(2*d2, 0), l1v(2*d2+1, 0));
            #pragma unroll
            for (int d2 = 0; d2 < 2; ++d2)
                Bv[1].d[d2] = pk(l1v(2*d2, 1), l1v(2*d2+1, 1));
            Bv[1].d[2] = ONE0; Bv[1].d[3] = Z2;

            f32x16 Dv;
            __builtin_amdgcn_s_setprio(1);
            Dv = __builtin_amdgcn_mfma_f32_32x32x16_f16(A2[0], Bv[0].v8, FZ, 0,0,0);
            Dv = __builtin_amdgcn_mfma_f32_32x32x16_f16(A2[1], Bv[1].v8, Dv, 0,0,0);
            __builtin_amdgcn_s_setprio(0);
            #pragma unroll
            for (int r = 0; r < 12; ++r) Dv[r] = tanh_fast(Dv[r]);

            #pragma unroll
            for (int d2 = 0; d2 < 2; ++d2) {
                float x0,y0,x1,y1;
                x0=Dv[2*d2]; y0=Dv[4+2*d2]; swap_halves(x0,y0);
                x1=Dv[2*d2+1]; y1=Dv[5+2*d2]; swap_halves(x1,y1);
                Bv[0].d[d2] = pk(x0,x1); Bv[0].d[2+d2] = pk(y0,y1);
            }
            Bv[1].d[0] = pk(Dv[8],Dv[9]); Bv[1].d[1] = pk(Dv[10],Dv[11]);
            Bv[1].d[2] = ONE0; Bv[1].d[3] = Z2;

            __builtin_amdgcn_s_setprio(1);
            Dv = __builtin_amdgcn_mfma_f32_32x32x16_f16(A3[0], Bv[0].v8, FZ, 0,0,0);
            Dv = __builtin_amdgcn_mfma_f32_32x32x16_f16(A3[1], Bv[1].v8, Dv, 0,0,0);
            __builtin_amdgcn_s_setprio(0);
            #pragma unroll
            for (int r = 0; r < 12; ++r) Dv[r] = tanh_fast(Dv[r]);

            float u = 0.f;
            #pragma unroll
            for (int j = 0; j < 6; ++j) {
                const float wa = (float)w4h[j][0], wb = (float)w4h[j][1];
                u = fmaf(wa, Dv[2*j], fmaf(wb, Dv[2*j+1], u));
            }
            u = xor32_sum(u) + b4v;
            const float dd = u - uT;
            if (h == 0 && valid) { if (isB) lbd += dd * dd; else li += dd * dd; }
        }
        block_reduce_atomic(li,  sums + 1);
        block_reduce_atomic(lbd, sums + 2);
    }
}

__global__ void k_zero(double* sums) {
    if (threadIdx.x < 3) sums[threadIdx.x] = 0.0;
}

__global__ void k_fin(const double* __restrict__ sums, float* __restrict__ out,
                      int N, int NI, int NB) {
    out[0] = (float)(sums[0] / (double)N + sums[1] / (double)NI + sums[2] / (double)NB);
}

extern "C" void kernel_launch(void* const* d_in, const int* in_sizes, int n_in,
                              void* d_out, int out_size, void* d_ws, size_t ws_size,
                              hipStream_t stream) {
    const float* t_c = (const float*)d_in[0];
    const float* x_c = (const float*)d_in[1];
    const float* t_i = (const float*)d_in[2];
    const float* x_i = (const float*)d_in[3];
    const float* u_i = (const float*)d_in[4];
    const float* t_b = (const float*)d_in[5];
    const float* x_b = (const float*)d_in[6];
    const float* u_b = (const float*)d_in[7];
    const float* W1  = (const float*)d_in[8];
    const float* b1  = (const float*)d_in[9];
    const float* W2  = (const float*)d_in[10];
    const float* b2  = (const float*)d_in[11];
    const float* W3  = (const float*)d_in[12];
    const float* b3  = (const float*)d_in[13];
    const float* W4  = (const float*)d_in[14];
    const float* b4  = (const float*)d_in[15];

    const int N  = in_sizes[0];
    const int NI = in_sizes[2];
    const int NB = in_sizes[5];
    const float nu = 0.0031830988618379067f;  // 0.01/pi

    // Persistent grid: 1024 blocks = 4 blocks/CU x 256 CUs (zero dispatch tail).
    // Split balances per-wave work: coll 62500 tiles vs data 12500 lighter tiles.
    const int CBLK = 936;
    const int DBLK = 88;

    double* sums = (double*)d_ws;

    k_zero<<<1, 64, 0, stream>>>(sums);
    k_fused<<<CBLK + DBLK, 256, 0, stream>>>(t_c, x_c, t_i, x_i, u_i, t_b, x_b, u_b,
                                             W1, b1, W2, b2, W3, b3, W4, b4,
                                             sums, N, NI, NB, CBLK, DBLK, nu);
    k_fin<<<1, 1, 0, stream>>>(sums, (float*)d_out, N, NI, NB);
}